// Round 14
// baseline (1729.357 us; speedup 1.0000x reference)
//
#include <hip/hip_runtime.h>

// Problem constants (fixed by reference)
#define BB 256      // batch
#define TT 1024     // time steps
#define HH 32       // hidden
#define SS 16       // superstep length (steps per barrier)
#define NBK (TT/SS) // 64 blocks
#define NSS (NBK+9) // 73 supersteps (10-stage skew)
#define NT 1024     // 16 waves (6 idle), 4 waves/SIMD
#define SP 32       // stream row stride (floats)
#define GP 96       // gi row stride

// R14 = R13 (343us) + three issue-count cuts, gh waves untouched:
//  (1) giA+giB merged (one wave does both row-dots; kills 24 duplicate
//      b128 reads/step),
//  (2) packed fp32 (v_pk_fma_f32 via float2 ext-vector + elementwise_fma)
//      in all feed-forward dots: 32 FMA -> 16 pk_fma,
//  (3) SIMD rebalance: S0..S2 = {gh_l + y_l}, S3 = {gi0,gi1,gi2,gather}.
//
// Superstep n schedule (one barrier per superstep):
//   wv15 : emb gather blk n     -> ebuf            (SIMD3)
//   wv4  : y1  blk n-1          -> y1s             (SIMD0)
//   wv5  : y2  blk n-2          -> y2s             (SIMD1)
//   wv6  : y3  blk n-3          -> y3s             (SIMD2)
//   wv3  : gi0 blk n-4          -> gib[0]          (SIMD3)
//   wv0  : gh0+gates blk n-5    -> h0s             (SIMD0, serial)
//   wv7  : gi1 blk n-6          -> gib[1]          (SIMD3)
//   wv1  : gh1+gates blk n-7    -> h1s             (SIMD1, serial)
//   wv11 : gi2 blk n-8          -> gib[2]          (SIMD3)
//   wv2  : gh2+gates blk n-9    -> out_seq         (SIMD2, serial)
//   wv8,9,10,12,13,14 : idle (barrier only)

typedef float v2f __attribute__((ext_vector_type(2)));

__device__ __forceinline__ float fast_rcp(float x) { return __builtin_amdgcn_rcpf(x); }
__device__ __forceinline__ float sigm(float x)     { return fast_rcp(1.f + __expf(-x)); }
__device__ __forceinline__ float tanh_fast(float x){ float e = __expf(2.f * x); return 1.f - 2.f * fast_rcp(e + 1.f); }
__device__ __forceinline__ float rlane(float v, int k) {
    return __int_as_float(__builtin_amdgcn_readlane(__float_as_int(v), k));
}

__global__ __launch_bounds__(NT, 4) void rnn_fused(
    const int*   __restrict__ xidx,   // [B,T]
    const float* __restrict__ hid,    // [L,B,H]
    const float* __restrict__ emb,    // [38000,H]
    const float* __restrict__ W1, const float* __restrict__ b1,
    const float* __restrict__ W2, const float* __restrict__ b2,
    const float* __restrict__ W3, const float* __restrict__ b3,
    const float* __restrict__ Wih,    // [L,3H,H]
    const float* __restrict__ Whh,    // [L,3H,H]
    const float* __restrict__ bih,    // [L,3H]
    const float* __restrict__ bhh,    // [L,3H]
    float*       __restrict__ out)    // [B*T*H] ++ [L*B*H]
{
    const int b   = blockIdx.x;
    const int tid = threadIdx.x;
    const int wv  = tid >> 6;
    const int ln  = tid & 63;
    const int lo  = ln & 31;

    __shared__ alignas(16) float ebuf[2][SS][SP];
    __shared__ alignas(16) float y1s [2][SS][SP];
    __shared__ alignas(16) float y2s [2][SS][SP];
    __shared__ alignas(16) float y3s [2][SS][SP];
    __shared__ alignas(16) float h0s [2][SS][SP];
    __shared__ alignas(16) float h1s [2][SS][SP];
    __shared__ alignas(16) float gib [3][2][SS][GP];

    // ---- roles ----
    const bool isGH = (wv < 3);                                  // layer = wv
    const bool isGI = (wv == 3 || wv == 7 || wv == 11);
    const int  il   = (wv == 3) ? 0 : (wv == 7) ? 1 : 2;
    const bool isY  = (wv >= 4 && wv <= 6);
    const int  ys   = wv - 4;
    const bool isE  = (wv == 15);

    // ---- register-resident weights ----
    float wA[32], wB[32];              // gh scalar weights
    v2f   wA2[16], wB2[16];            // ff packed weights
    float biasA = 0.f, biasB = 0.f, v_h = 0.f;

    if (isGH) {
        const float4* pA = reinterpret_cast<const float4*>(Whh + (size_t)(wv * 96 + ln) * HH);
        const float4* pB = reinterpret_cast<const float4*>(Whh + (size_t)(wv * 96 + 64 + lo) * HH);
        #pragma unroll
        for (int i = 0; i < 8; ++i) {
            reinterpret_cast<float4*>(wA)[i] = pA[i];
            reinterpret_cast<float4*>(wB)[i] = pB[i];
        }
        biasA = bhh[wv * 96 + ln];
        biasB = bhh[wv * 96 + 64 + lo];
        if (ln < HH) v_h = hid[(size_t)(wv * BB + b) * HH + ln];
    } else if (isGI) {
        const v2f* pA = reinterpret_cast<const v2f*>(Wih + (size_t)(il * 96 + ln) * HH);
        const v2f* pB = reinterpret_cast<const v2f*>(Wih + (size_t)(il * 96 + 64 + lo) * HH);
        #pragma unroll
        for (int i = 0; i < 16; ++i) { wA2[i] = pA[i]; wB2[i] = pB[i]; }
        biasA = bih[il * 96 + ln];
        biasB = bih[il * 96 + 64 + lo];
    } else if (isY) {
        const float* Ws = (ys == 0) ? W1 : (ys == 1) ? W2 : W3;
        const float* bs = (ys == 0) ? b1 : (ys == 1) ? b2 : b3;
        const v2f* pA = reinterpret_cast<const v2f*>(Ws + (size_t)lo * HH);
        #pragma unroll
        for (int i = 0; i < 16; ++i) wA2[i] = pA[i];
        biasA = bs[lo];
    }
    __syncthreads();

    float* const out_seq = out + (size_t)b * TT * HH;
    float* const out_hf  = out + (size_t)BB * TT * HH;

    for (int n = 0; n < NSS; ++n) {
        if (isGH) {
            // ============ gh wave, layer wv: 16 serial steps (UNCHANGED) =======
            const int blk = n - 5 - 2 * wv;
            if (blk >= 0 && blk < NBK) {
                const int p = blk & 1;
                const float* gsrc = &gib[wv][p][0][0];
                for (int t2 = 0; t2 < SS; ++t2) {
                    const float giA = gsrc[t2 * GP + ln];        // r/z rows
                    const float giB = gsrc[t2 * GP + 64 + lo];   // n rows
                    float a0 = biasA, a1 = 0.f, c0 = biasB, c1 = 0.f;
                    #pragma unroll
                    for (int k = 0; k < 32; k += 2) {
                        const float h0 = rlane(v_h, k), h1 = rlane(v_h, k + 1);
                        a0 = fmaf(wA[k],     h0, a0);
                        a1 = fmaf(wA[k + 1], h1, a1);
                        c0 = fmaf(wB[k],     h0, c0);
                        c1 = fmaf(wB[k + 1], h1, c1);
                    }
                    const float sA  = giA + a0 + a1;     // r-pre / z-pre
                    const float ghB = c0 + c1;           // h_n
                    const float zp  = __shfl_xor(sA, 32);
                    const float r   = sigm(sA);
                    const float z   = sigm(zp);
                    const float nn  = tanh_fast(fmaf(r, ghB, giB));
                    const float hn  = fmaf(z, v_h - nn, nn);
                    v_h = hn;
                    if (ln < HH) {
                        if (wv == 0)      h0s[p][t2][ln] = hn;
                        else if (wv == 1) h1s[p][t2][ln] = hn;
                        else out_seq[(size_t)(blk * SS + t2) * HH + ln] = hn;
                    }
                }
            }
        } else if (isGI) {
            // ============ merged gi wave, layer il: pk_fma, A+B rows ===========
            const int blk = n - 4 - 2 * il;
            if (blk >= 0 && blk < NBK) {
                const int p = blk & 1;
                const float* xs = (il == 0) ? &y3s[p][0][0]
                                : (il == 1) ? &h0s[p][0][0]
                                            : &h1s[p][0][0];
                float* gdst = &gib[il][p][0][0];
                for (int t2 = 0; t2 < SS; ++t2) {
                    const float4* xr = reinterpret_cast<const float4*>(xs + t2 * SP);
                    v2f aA0 = {biasA, 0.f}, aA1 = {0.f, 0.f};
                    v2f aB0 = {biasB, 0.f}, aB1 = {0.f, 0.f};
                    #pragma unroll
                    for (int j = 0; j < 8; ++j) {
                        const float4 xv = xr[j];            // uniform -> broadcast
                        v2f xlo, xhi;
                        xlo.x = xv.x; xlo.y = xv.y;
                        xhi.x = xv.z; xhi.y = xv.w;
                        aA0 = __builtin_elementwise_fma(wA2[2 * j],     xlo, aA0);
                        aA1 = __builtin_elementwise_fma(wA2[2 * j + 1], xhi, aA1);
                        aB0 = __builtin_elementwise_fma(wB2[2 * j],     xlo, aB0);
                        aB1 = __builtin_elementwise_fma(wB2[2 * j + 1], xhi, aB1);
                    }
                    gdst[t2 * GP + ln] = (aA0.x + aA0.y) + (aA1.x + aA1.y);
                    if (ln < 32)
                        gdst[t2 * GP + 64 + ln] = (aB0.x + aB0.y) + (aB1.x + aB1.y);
                }
            }
        } else if (isY) {
            // ============ y wave, stage ys: pk_fma =============================
            const int blk = n - 1 - ys;
            if (blk >= 0 && blk < NBK) {
                const int p = blk & 1;
                const float* xs = (ys == 0) ? &ebuf[p][0][0]
                                : (ys == 1) ? &y1s[p][0][0]
                                            : &y2s[p][0][0];
                float* dst = (ys == 0) ? &y1s[p][0][0]
                           : (ys == 1) ? &y2s[p][0][0]
                                       : &y3s[p][0][0];
                for (int t2 = 0; t2 < SS; ++t2) {
                    const float4* xr = reinterpret_cast<const float4*>(xs + t2 * SP);
                    v2f a0 = {biasA, 0.f}, a1 = {0.f, 0.f};
                    #pragma unroll
                    for (int j = 0; j < 8; ++j) {
                        const float4 xv = xr[j];
                        v2f xlo, xhi;
                        xlo.x = xv.x; xlo.y = xv.y;
                        xhi.x = xv.z; xhi.y = xv.w;
                        a0 = __builtin_elementwise_fma(wA2[2 * j],     xlo, a0);
                        a1 = __builtin_elementwise_fma(wA2[2 * j + 1], xhi, a1);
                    }
                    const float y = fmaxf((a0.x + a0.y) + (a1.x + a1.y), 0.f);
                    if (ln < 32) dst[t2 * SP + ln] = y;
                }
            }
        } else if (isE) {
            // ============ emb gather blk n =====================================
            if (n < NBK) {
                const int pe = n & 1, t0 = n * SS;
                #pragma unroll
                for (int k = 0; k < 2; ++k) {
                    const int task = k * 64 + ln;   // 128 tasks: 16 rows x 8 chunks
                    const int row = task >> 3, qq = task & 7;
                    const int tok = xidx[b * TT + t0 + row];
                    const float4 v = *reinterpret_cast<const float4*>(emb + (size_t)tok * HH + qq * 4);
                    *reinterpret_cast<float4*>(&ebuf[pe][row][qq * 4]) = v;
                }
            }
        }
        // wv 8,9,10,12,13,14: idle
        __syncthreads();   // one barrier per 16 steps
    }

    if (isGH && ln < HH)
        out_hf[(size_t)(wv * BB + b) * HH + ln] = v_h;
}

extern "C" void kernel_launch(void* const* d_in, const int* in_sizes, int n_in,
                              void* d_out, int out_size, void* d_ws, size_t ws_size,
                              hipStream_t stream) {
    const int*   x   = (const int*)  d_in[0];
    const float* hid = (const float*)d_in[1];
    const float* emb = (const float*)d_in[2];
    const float* W1  = (const float*)d_in[3];
    const float* b1  = (const float*)d_in[4];
    const float* W2  = (const float*)d_in[5];
    const float* b2  = (const float*)d_in[6];
    const float* W3  = (const float*)d_in[7];
    const float* b3  = (const float*)d_in[8];
    const float* Wih = (const float*)d_in[9];
    const float* Whh = (const float*)d_in[10];
    const float* bih = (const float*)d_in[11];
    const float* bhh = (const float*)d_in[12];

    rnn_fused<<<dim3(BB), dim3(NT), 0, stream>>>(
        x, hid, emb, W1, b1, W2, b2, W3, b3, Wih, Whh, bih, bhh, (float*)d_out);
}

// Round 15
// 348.718 us; speedup vs baseline: 4.9592x; 4.9592x over previous
//
#include <hip/hip_runtime.h>

// Problem constants (fixed by reference)
#define BB 256      // batch
#define TT 1024     // time steps
#define HH 32       // hidden
#define SS 16       // superstep length (steps per barrier)
#define NBK (TT/SS) // 64 blocks
#define NSS (NBK+9) // 73 supersteps (10-stage skew)
#define NT 1024     // 16 waves, 4/SIMD
#define SP 32       // stream row stride (floats)
#define GP 96       // gi row stride

// R15 = R13 (343us, best) + pure SCHEDULING changes (no new register structs;
// R12/R14 both died to spill from register-structure growth):
//  (1) wave->SIMD remap so each gh wave has a near-private SIMD:
//      S0: gh0 + y1 + gather | S1: gh1 + y2 + giA0 | S2: gh2 + y3 + giB0
//      S3: giA1 + giB1 + giA2 + giB2
//  (2) gh loop software-pipelines the per-step gib LDS reads by one step.
//
// Superstep n schedule (one barrier per superstep), stage -> wave:
//   emb gather blk n   -> wv8      y1 blk n-1 -> wv4
//   y2 blk n-2         -> wv5      y3 blk n-3 -> wv6
//   gi0 blk n-4        -> wv9(A) + wv10(B)
//   gh0 blk n-5        -> wv0
//   gi1 blk n-6        -> wv3(A) + wv7(B)
//   gh1 blk n-7        -> wv1
//   gi2 blk n-8        -> wv11(A) + wv15(B)
//   gh2 blk n-9        -> wv2
//   idle: wv12, wv13, wv14

__device__ __forceinline__ float fast_rcp(float x) { return __builtin_amdgcn_rcpf(x); }
__device__ __forceinline__ float sigm(float x)     { return fast_rcp(1.f + __expf(-x)); }
__device__ __forceinline__ float tanh_fast(float x){ float e = __expf(2.f * x); return 1.f - 2.f * fast_rcp(e + 1.f); }
__device__ __forceinline__ float rlane(float v, int k) {
    return __int_as_float(__builtin_amdgcn_readlane(__float_as_int(v), k));
}

__global__ __launch_bounds__(NT, 4) void rnn_fused(
    const int*   __restrict__ xidx,   // [B,T]
    const float* __restrict__ hid,    // [L,B,H]
    const float* __restrict__ emb,    // [38000,H]
    const float* __restrict__ W1, const float* __restrict__ b1,
    const float* __restrict__ W2, const float* __restrict__ b2,
    const float* __restrict__ W3, const float* __restrict__ b3,
    const float* __restrict__ Wih,    // [L,3H,H]
    const float* __restrict__ Whh,    // [L,3H,H]
    const float* __restrict__ bih,    // [L,3H]
    const float* __restrict__ bhh,    // [L,3H]
    float*       __restrict__ out)    // [B*T*H] ++ [L*B*H]
{
    const int b   = blockIdx.x;
    const int tid = threadIdx.x;
    const int wv  = tid >> 6;
    const int ln  = tid & 63;
    const int lo  = ln & 31;

    __shared__ alignas(16) float ebuf[2][SS][SP];
    __shared__ alignas(16) float y1s [2][SS][SP];
    __shared__ alignas(16) float y2s [2][SS][SP];
    __shared__ alignas(16) float y3s [2][SS][SP];
    __shared__ alignas(16) float h0s [2][SS][SP];
    __shared__ alignas(16) float h1s [2][SS][SP];
    __shared__ alignas(16) float gib [3][2][SS][GP];

    // ---- roles (wave->SIMD = wv%4) ----
    const bool isGH = (wv < 3);                                    // layer = wv
    const bool isY  = (wv >= 4 && wv <= 6);
    const int  ys   = wv - 4;
    const bool isGA = (wv == 9 || wv == 3 || wv == 11);            // gi rows 0-63
    const bool isGB = (wv == 10 || wv == 7 || wv == 15);           // gi rows 64-95
    const int  gl   = (wv == 9 || wv == 10) ? 0
                    : (wv == 3 || wv == 7)  ? 1 : 2;               // gi layer
    const bool isE  = (wv == 8);

    // ---- register-resident weights (identical structure to R13) ----
    float wA[32], wB[32];
    float biasA = 0.f, biasB = 0.f, v_h = 0.f;

    if (isGH) {
        const float4* pA = reinterpret_cast<const float4*>(Whh + (size_t)(wv * 96 + ln) * HH);
        const float4* pB = reinterpret_cast<const float4*>(Whh + (size_t)(wv * 96 + 64 + lo) * HH);
        #pragma unroll
        for (int i = 0; i < 8; ++i) {
            reinterpret_cast<float4*>(wA)[i] = pA[i];
            reinterpret_cast<float4*>(wB)[i] = pB[i];
        }
        biasA = bhh[wv * 96 + ln];
        biasB = bhh[wv * 96 + 64 + lo];
        if (ln < HH) v_h = hid[(size_t)(wv * BB + b) * HH + ln];
    } else if (isGA) {
        const float4* pA = reinterpret_cast<const float4*>(Wih + (size_t)(gl * 96 + ln) * HH);
        #pragma unroll
        for (int i = 0; i < 8; ++i) reinterpret_cast<float4*>(wA)[i] = pA[i];
        biasA = bih[gl * 96 + ln];
    } else if (isGB) {
        const float4* pA = reinterpret_cast<const float4*>(Wih + (size_t)(gl * 96 + 64 + lo) * HH);
        #pragma unroll
        for (int i = 0; i < 8; ++i) reinterpret_cast<float4*>(wA)[i] = pA[i];
        biasA = bih[gl * 96 + 64 + lo];
    } else if (isY) {
        const float* Ws = (ys == 0) ? W1 : (ys == 1) ? W2 : W3;
        const float* bs = (ys == 0) ? b1 : (ys == 1) ? b2 : b3;
        const float4* pA = reinterpret_cast<const float4*>(Ws + (size_t)lo * HH);
        #pragma unroll
        for (int i = 0; i < 8; ++i) reinterpret_cast<float4*>(wA)[i] = pA[i];
        biasA = bs[lo];
    }
    __syncthreads();

    float* const out_seq = out + (size_t)b * TT * HH;
    float* const out_hf  = out + (size_t)BB * TT * HH;

    for (int n = 0; n < NSS; ++n) {
        if (isGH) {
            // ===== gh wave, layer wv: 16 serial steps, gi reads pipelined ======
            const int blk = n - 5 - 2 * wv;
            if (blk >= 0 && blk < NBK) {
                const int p = blk & 1;
                const float* gsrc = &gib[wv][p][0][0];
                float giA = gsrc[ln];            // prefetch step 0
                float giB = gsrc[64 + lo];
                for (int t2 = 0; t2 < SS; ++t2) {
                    float giA_n = 0.f, giB_n = 0.f;
                    if (t2 + 1 < SS) {           // prefetch next step's gi
                        giA_n = gsrc[(t2 + 1) * GP + ln];
                        giB_n = gsrc[(t2 + 1) * GP + 64 + lo];
                    }
                    float a0 = biasA, a1 = 0.f, c0 = biasB, c1 = 0.f;
                    #pragma unroll
                    for (int k = 0; k < 32; k += 2) {
                        const float h0 = rlane(v_h, k), h1 = rlane(v_h, k + 1);
                        a0 = fmaf(wA[k],     h0, a0);
                        a1 = fmaf(wA[k + 1], h1, a1);
                        c0 = fmaf(wB[k],     h0, c0);
                        c1 = fmaf(wB[k + 1], h1, c1);
                    }
                    const float sA  = giA + a0 + a1;     // r-pre / z-pre
                    const float ghB = c0 + c1;           // h_n
                    const float zp  = __shfl_xor(sA, 32);
                    const float r   = sigm(sA);
                    const float z   = sigm(zp);
                    const float nn  = tanh_fast(fmaf(r, ghB, giB));
                    const float hn  = fmaf(z, v_h - nn, nn);
                    v_h = hn;
                    if (ln < HH) {
                        if (wv == 0)      h0s[p][t2][ln] = hn;
                        else if (wv == 1) h1s[p][t2][ln] = hn;
                        else out_seq[(size_t)(blk * SS + t2) * HH + ln] = hn;
                    }
                    giA = giA_n;
                    giB = giB_n;
                }
            }
        } else if (isGA) {
            // ===== giA wave, layer gl: rows 0-63, uniform-b128 broadcast =======
            const int blk = n - 4 - 2 * gl;
            if (blk >= 0 && blk < NBK) {
                const int p = blk & 1;
                const float* xs = (gl == 0) ? &y3s[p][0][0]
                                : (gl == 1) ? &h0s[p][0][0]
                                            : &h1s[p][0][0];
                float* gdst = &gib[gl][p][0][0];
                for (int t2 = 0; t2 < SS; ++t2) {
                    const float4* xr = reinterpret_cast<const float4*>(xs + t2 * SP);
                    float a0 = biasA, a1 = 0.f, a2 = 0.f, a3 = 0.f;
                    #pragma unroll
                    for (int j = 0; j < 8; ++j) {
                        const float4 xv = xr[j];          // uniform addr -> broadcast
                        a0 = fmaf(wA[4 * j + 0], xv.x, a0);
                        a1 = fmaf(wA[4 * j + 1], xv.y, a1);
                        a2 = fmaf(wA[4 * j + 2], xv.z, a2);
                        a3 = fmaf(wA[4 * j + 3], xv.w, a3);
                    }
                    gdst[t2 * GP + ln] = (a0 + a1) + (a2 + a3);
                }
            }
        } else if (isGB) {
            // ===== giB wave, layer gl: rows 64-95 (n-gates) ====================
            const int blk = n - 4 - 2 * gl;
            if (blk >= 0 && blk < NBK) {
                const int p = blk & 1;
                const float* xs = (gl == 0) ? &y3s[p][0][0]
                                : (gl == 1) ? &h0s[p][0][0]
                                            : &h1s[p][0][0];
                float* gdst = &gib[gl][p][0][0];
                for (int t2 = 0; t2 < SS; ++t2) {
                    const float4* xr = reinterpret_cast<const float4*>(xs + t2 * SP);
                    float a0 = biasA, a1 = 0.f, a2 = 0.f, a3 = 0.f;
                    #pragma unroll
                    for (int j = 0; j < 8; ++j) {
                        const float4 xv = xr[j];
                        a0 = fmaf(wA[4 * j + 0], xv.x, a0);
                        a1 = fmaf(wA[4 * j + 1], xv.y, a1);
                        a2 = fmaf(wA[4 * j + 2], xv.z, a2);
                        a3 = fmaf(wA[4 * j + 3], xv.w, a3);
                    }
                    if (ln < 32) gdst[t2 * GP + 64 + ln] = (a0 + a1) + (a2 + a3);
                }
            }
        } else if (isY) {
            // ===== y1/y2/y3 waves ==============================================
            const int blk = n - 1 - ys;
            if (blk >= 0 && blk < NBK) {
                const int p = blk & 1;
                const float* xs = (ys == 0) ? &ebuf[p][0][0]
                                : (ys == 1) ? &y1s[p][0][0]
                                            : &y2s[p][0][0];
                float* dst = (ys == 0) ? &y1s[p][0][0]
                           : (ys == 1) ? &y2s[p][0][0]
                                       : &y3s[p][0][0];
                for (int t2 = 0; t2 < SS; ++t2) {
                    const float4* xr = reinterpret_cast<const float4*>(xs + t2 * SP);
                    float a0 = biasA, a1 = 0.f, a2 = 0.f, a3 = 0.f;
                    #pragma unroll
                    for (int j = 0; j < 8; ++j) {
                        const float4 xv = xr[j];
                        a0 = fmaf(wA[4 * j + 0], xv.x, a0);
                        a1 = fmaf(wA[4 * j + 1], xv.y, a1);
                        a2 = fmaf(wA[4 * j + 2], xv.z, a2);
                        a3 = fmaf(wA[4 * j + 3], xv.w, a3);
                    }
                    const float y = fmaxf((a0 + a1) + (a2 + a3), 0.f);
                    if (ln < 32) dst[t2 * SP + ln] = y;
                }
            }
        } else if (isE) {
            // ===== emb gather blk n ============================================
            if (n < NBK) {
                const int pe = n & 1, t0 = n * SS;
                #pragma unroll
                for (int k = 0; k < 2; ++k) {
                    const int task = k * 64 + ln;   // 128 tasks: 16 rows x 8 chunks
                    const int row = task >> 3, qq = task & 7;
                    const int tok = xidx[b * TT + t0 + row];
                    const float4 v = *reinterpret_cast<const float4*>(emb + (size_t)tok * HH + qq * 4);
                    *reinterpret_cast<float4*>(&ebuf[pe][row][qq * 4]) = v;
                }
            }
        }
        // wv 12,13,14: idle
        __syncthreads();   // one barrier per 16 steps
    }

    if (isGH && ln < HH)
        out_hf[(size_t)(wv * BB + b) * HH + ln] = v_h;
}

extern "C" void kernel_launch(void* const* d_in, const int* in_sizes, int n_in,
                              void* d_out, int out_size, void* d_ws, size_t ws_size,
                              hipStream_t stream) {
    const int*   x   = (const int*)  d_in[0];
    const float* hid = (const float*)d_in[1];
    const float* emb = (const float*)d_in[2];
    const float* W1  = (const float*)d_in[3];
    const float* b1  = (const float*)d_in[4];
    const float* W2  = (const float*)d_in[5];
    const float* b2  = (const float*)d_in[6];
    const float* W3  = (const float*)d_in[7];
    const float* b3  = (const float*)d_in[8];
    const float* Wih = (const float*)d_in[9];
    const float* Whh = (const float*)d_in[10];
    const float* bih = (const float*)d_in[11];
    const float* bhh = (const float*)d_in[12];

    rnn_fused<<<dim3(BB), dim3(NT), 0, stream>>>(
        x, hid, emb, W1, b1, W2, b2, W3, b3, Wih, Whh, bih, bhh, (float*)d_out);
}